// Round 12
// baseline (12959.048 us; speedup 1.0000x reference)
//
#include <hip/hip_runtime.h>
#include <math.h>

#define BB   256
#define HH   512
#define TT   64
#define NOUT 33
#define CD   128
#define NTHR 1024
#define LOFF (4*HH*HH)

#define HUT  8          // hu per WG
#define BT   64         // batch cols per WG
#define ABUF 131072     // floats per chunked activation buffer [kc 128][b 256][4]
#define FC2OFF 4194304  // float offset of fc2 section inside wsT

typedef float f16v __attribute__((ext_vector_type(16)));
typedef const __attribute__((address_space(4))) float cfloat;
typedef const __attribute__((address_space(4))) f16v  cf16v;

__device__ __forceinline__ float sigm(float x)  { return 1.0f/(1.0f+expf(-x)); }
__device__ __forceinline__ float lrelu(float x) { return x >= 0.0f ? x : 0.01f*x; }

// memory-side coherent (cross-XCD) access, no fences needed (proven R11)
__device__ __forceinline__ float gld(const float* p) {
  return __hip_atomic_load(p, __ATOMIC_RELAXED, __HIP_MEMORY_SCOPE_AGENT);
}
__device__ __forceinline__ void gst(float* p, float v) {
  __hip_atomic_store(p, v, __ATOMIC_RELAXED, __HIP_MEMORY_SCOPE_AGENT);
}
__device__ __forceinline__ unsigned gldu(const unsigned* p) {
  return __hip_atomic_load(p, __ATOMIC_RELAXED, __HIP_MEMORY_SCOPE_AGENT);
}

// provably-uniform constant-AS pointer -> compiler emits s_load (proven R10/R11)
__device__ __forceinline__ cfloat* cptr(const float* p) {
  unsigned long long u = (unsigned long long)p;
  unsigned lo = __builtin_amdgcn_readfirstlane((unsigned)u);
  unsigned hi = __builtin_amdgcn_readfirstlane((unsigned)(u >> 32));
  return (cfloat*)((((unsigned long long)hi) << 32) | (unsigned long long)lo);
}

// j-group barrier: 64 WGs sharing a batch slice. Monotonic counter + gen.
__device__ __forceinline__ void gbar(unsigned* bar, unsigned ep, int j) {
  __syncthreads();
  if (threadIdx.x == 0) {
    unsigned old = __hip_atomic_fetch_add(&bar[j*32], 1u, __ATOMIC_RELAXED, __HIP_MEMORY_SCOPE_AGENT);
    if (old == ep*64u + 63u)
      __hip_atomic_store(&bar[j*32+16], ep+1u, __ATOMIC_RELAXED, __HIP_MEMORY_SCOPE_AGENT);
    while (gldu(&bar[j*32+16]) < ep+1u) __builtin_amdgcn_s_sleep(1);
  }
  __syncthreads();
}

// ---- weight transpose pre-kernel ----
// layer section per i-slice: [l 2][a 2][o 4][kc 128][r8 8][kj 4]  (65536 floats)
// fc2 section per i-slice:   [kc 128][r8 8][kj 4]                 (4096 floats)
extern "C" __global__ void __launch_bounds__(256)
transpose_weights(const float* __restrict__ Wih, const float* __restrict__ Whh,
                  const float* __restrict__ fc2W, float* __restrict__ wsT)
{
  const int i = blockIdx.x, tid = threadIdx.x;
  #pragma unroll 1
  for (int idx = tid; idx < 65536; idx += 256) {
    int kj = idx & 3, r8 = (idx>>2)&7, kc = (idx>>5)&127, o = (idx>>12)&3, a = (idx>>14)&1, l = idx>>15;
    int hu = i*HUT + 2*o + (r8>>2), g = r8&3, k = kc*4+kj;
    const float* src = a ? Whh : Wih;
    wsT[(size_t)i*65536 + idx] = src[(size_t)l*LOFF + (size_t)(g*HH + hu)*HH + k];
  }
  #pragma unroll 1
  for (int idx = tid; idx < 4096; idx += 256) {
    int kj = idx & 3, r8 = (idx>>2)&7, kc = idx>>5;
    wsT[(size_t)FC2OFF + i*4096 + idx] = fc2W[(size_t)(i*HUT + r8)*HH + kc*4+kj];
  }
}

// ---- staging: wave wv owns 4 chunks of a 64-chunk half-tile ----
__device__ __forceinline__ void stage_load(const float* src, int kcBase, int wv, int bglob, float4* st) {
  #pragma unroll
  for (int q = 0; q < 4; ++q) {
    const float* p = src + (size_t)((kcBase + wv*4 + q)*256 + bglob)*4;
    st[q].x = gld(p); st[q].y = gld(p+1); st[q].z = gld(p+2); st[q].w = gld(p+3);
  }
  __builtin_amdgcn_sched_barrier(0);   // keep loads issued here (latency hides under FMA)
}
__device__ __forceinline__ void stage_write(float* buf, int wv, int lane, const float4* st) {
  #pragma unroll
  for (int q = 0; q < 4; ++q)
    *(float4*)(buf + (wv*4+q)*256 + lane*4) = st[q];
}

// consume CNT chunks: per chunk, 4 k-values (LDS b128) x 8 gate-rows (SGPR weights)
template<int CNT>
__device__ __forceinline__ void consume(const float* buf, cfloat* wb, int cstart, int lane, float* acc) {
  #pragma unroll 1
  for (int m = 0; m < CNT; ++m) {
    int cL = cstart + m;
    float4 q = *(const float4*)(buf + cL*256 + lane*4);
    cf16v* wp = (cf16v*)(wb + (size_t)cL*32);
    f16v wA = wp[0], wB = wp[1];
    #pragma unroll
    for (int r = 0; r < 4; ++r) {
      acc[r]   += wA[r*4+0]*q.x + wA[r*4+1]*q.y + wA[r*4+2]*q.z + wA[r*4+3]*q.w;
      acc[4+r] += wB[r*4+0]*q.x + wB[r*4+1]*q.y + wB[r*4+2]*q.z + wB[r*4+3]*q.w;
    }
  }
}

// one LSTM layer phase: 4 half-tiles (x lo/hi, h lo/hi) pipelined through 2 LDS buffers
__device__ __forceinline__ void layer_phase(const float* xsrc, const float* hsrc,
    const float* wsTL, float* hdst, float& creg, const float* ldsb,
    float* T, int tid, int Bbase, int hugBase)
{
  const int lane = tid & 63, wv = tid >> 6;
  const int o = wv & 3, sub = wv >> 2;
  float* buf0 = T;
  float* buf1 = T + 16384;
  float acc[8];
  #pragma unroll
  for (int r = 0; r < 8; ++r) acc[r] = 0.f;
  cfloat* wx0 = cptr(wsTL + o*4096);
  cfloat* wx1 = cptr(wsTL + o*4096 + 2048);
  cfloat* wh0 = cptr(wsTL + 16384 + o*4096);
  cfloat* wh1 = cptr(wsTL + 16384 + o*4096 + 2048);

  float4 st[4];
  stage_load(xsrc, 0, wv, Bbase + lane, st);
  stage_write(buf0, wv, lane, st);
  __syncthreads();
  stage_load(xsrc, 64, wv, Bbase + lane, st);
  consume<16>(buf0, wx0, sub*16, lane, acc);
  stage_write(buf1, wv, lane, st);
  __syncthreads();
  stage_load(hsrc, 0, wv, Bbase + lane, st);
  consume<16>(buf1, wx1, sub*16, lane, acc);
  stage_write(buf0, wv, lane, st);
  __syncthreads();
  stage_load(hsrc, 64, wv, Bbase + lane, st);
  consume<16>(buf0, wh0, sub*16, lane, acc);
  stage_write(buf1, wv, lane, st);
  __syncthreads();
  consume<16>(buf1, wh1, sub*16, lane, acc);
  __syncthreads();
  #pragma unroll
  for (int r = 0; r < 8; ++r) T[(sub*32 + o*8 + r)*64 + lane] = acc[r];
  __syncthreads();
  if (tid < 512) {
    int hu = tid >> 6, b = tid & 63;
    float g[4];
    #pragma unroll
    for (int gg = 0; gg < 4; ++gg) {
      int gr = hu*4 + gg;
      float s = ldsb[gr];
      #pragma unroll
      for (int sb = 0; sb < 4; ++sb) s += T[(sb*32 + gr)*64 + b];
      g[gg] = s;
    }
    float ig = sigm(g[0]), fg = sigm(g[1]), gv = tanhf(g[2]), og = sigm(g[3]);
    float cn = fg*creg + ig*gv;
    creg = cn;
    int hug = hugBase + hu, bg = Bbase + b;
    gst(hdst + (size_t)((hug>>2)*256 + bg)*4 + (hug&3), og*tanhf(cn));
  }
  __syncthreads();
}

// fc2 phase: 2 half-tiles of h2, 8 output rows, k split over 16 waves
__device__ __forceinline__ void fc2_phase(const float* h2src, const float* wsTf,
    float* ybuf, const float* lds_bc, float condY, float* T, int tid, int Bbase, int hugBase)
{
  const int lane = tid & 63, wv = tid >> 6;
  float* buf0 = T;
  float* buf1 = T + 16384;
  float acc[8];
  #pragma unroll
  for (int r = 0; r < 8; ++r) acc[r] = 0.f;
  cfloat* w0 = cptr(wsTf);
  cfloat* w1 = cptr(wsTf + 2048);

  float4 st[4];
  stage_load(h2src, 0, wv, Bbase + lane, st);
  stage_write(buf0, wv, lane, st);
  __syncthreads();
  stage_load(h2src, 64, wv, Bbase + lane, st);
  consume<4>(buf0, w0, wv*4, lane, acc);
  stage_write(buf1, wv, lane, st);
  __syncthreads();
  consume<4>(buf1, w1, wv*4, lane, acc);
  __syncthreads();
  #pragma unroll
  for (int r = 0; r < 8; ++r) T[(wv*8 + r)*64 + lane] = acc[r];
  __syncthreads();
  if (tid < 512) {
    int row = tid >> 6, b = tid & 63;
    float s = lds_bc[row] + condY;
    #pragma unroll
    for (int w16 = 0; w16 < 16; ++w16) s += T[(w16*8 + row)*64 + b];
    int rg = hugBase + row, bg = Bbase + b;
    gst(ybuf + (size_t)((rg>>2)*256 + bg)*4 + (rg&3), lrelu(s));
  }
  __syncthreads();
}

extern "C" __global__ void __launch_bounds__(NTHR)
decoder_kernel(const float* __restrict__ h0, const float* __restrict__ c0,
               const float* __restrict__ conds, const float* __restrict__ emb,
               const float* __restrict__ bih, const float* __restrict__ bhh,
               const float* __restrict__ fcW, const float* __restrict__ fcb,
               const float* __restrict__ fc2b, const float* __restrict__ fc3W,
               const float* __restrict__ fc3b,
               float* __restrict__ out, unsigned* bar, float* wsf)
{
  const int w = blockIdx.x;
  const int i = w & 63, j = w >> 6;     // wg%8 == i%8 -> weight slices L2-local per XCD
  const int tid = threadIdx.x;
  const int lane = tid & 63, wv = tid >> 6;
  const int Bbase = j*BT;
  const int hugBase = i*HUT;

  float* xbuf = wsf;
  float* h1a = wsf + 1*ABUF;
  float* h1b = wsf + 2*ABUF;
  float* h2a = wsf + 3*ABUF;
  float* h2b = wsf + 4*ABUF;
  float* ybuf = wsf + 5*ABUF;
  const float* wsT  = wsf + 6*ABUF;
  const float* wsTf = wsT + FC2OFF + i*4096;

  __shared__ float4 T4[8192];           // 128KB: staging tiles + partial-sum overlay
  float* T = (float*)T4;
  __shared__ float lds_y[HH];
  __shared__ float part[NOUT][17];
  __shared__ float lds_b1[32], lds_b2[32], lds_bc[8];
  __shared__ int   lds_act;

  // ---- biases ----
  if (tid < 32) {
    int hu = hugBase + (tid>>2), g = tid&3;
    lds_b1[tid] = bih[g*HH+hu] + bhh[g*HH+hu];
    lds_b2[tid] = bih[4*HH + g*HH+hu] + bhh[4*HH + g*HH+hu];
  }
  if (tid < 8) lds_bc[tid] = fc2b[hugBase + tid];

  // ---- state init (chunked layouts, sc stores) ----
  float c1 = 0.f, c2 = 0.f;
  if (tid < 512) {
    int hu = tid>>6, b = tid&63;
    int hug = hugBase + hu, bg = Bbase + b;
    c1 = c0[(size_t)bg*HH + hug];
    c2 = c0[(size_t)(BB+bg)*HH + hug];
    gst(h1a + (size_t)((hug>>2)*256 + bg)*4 + (hug&3), h0[(size_t)bg*HH+hug]);
    gst(h2a + (size_t)((hug>>2)*256 + bg)*4 + (hug&3), h0[(size_t)(BB+bg)*HH+hug]);
  }
  #pragma unroll 1
  for (int it = 0; it < 32; ++it) {     // x0 = [emb[SOS=0] | dur=0]
    int idx = tid + it*1024;
    int kj = idx&3, b = (idx>>2)&63, kc = idx>>8;
    int k = kc*4+kj;
    gst(xbuf + (size_t)(kc*256 + Bbase+b)*4 + kj, (k < HH-1) ? emb[k] : 0.0f);
  }

  // ---- condb tile (local compute) -> condY register ----
  {
    int b = tid&63, kcg = tid>>6;
    const float* crow = conds + (size_t)(Bbase+b)*CD;
    #pragma unroll 1
    for (int it = 0; it < 8; ++it) {
      int kc = kcg + it*16;
      float4 v;
      #pragma unroll
      for (int kj = 0; kj < 4; ++kj) {
        int k = kc*4+kj;
        const float* fr = fcW + (size_t)k*CD;
        float s = fcb[k];
        #pragma unroll 4
        for (int q = 0; q < CD; q += 4)
          s += fr[q]*crow[q] + fr[q+1]*crow[q+1] + fr[q+2]*crow[q+2] + fr[q+3]*crow[q+3];
        ((float*)&v)[kj] = lrelu(s);
      }
      *(float4*)(T + kc*256 + b*4) = v;
    }
  }
  __syncthreads();
  float condY = 0.f;
  {
    float accy[8];
    #pragma unroll
    for (int r = 0; r < 8; ++r) accy[r] = 0.f;
    consume<8>(T, cptr(wsTf), wv*8, lane, accy);
    __syncthreads();
    #pragma unroll
    for (int r = 0; r < 8; ++r) T[(wv*8+r)*64 + lane] = accy[r];
    __syncthreads();
    if (tid < 512) {
      int row = tid>>6, b = tid&63;
      #pragma unroll
      for (int w16 = 0; w16 < 16; ++w16) condY += T[(w16*8+row)*64 + b];
    }
  }

  unsigned ep = 0;
  gbar(bar, ep++, j);

  for (int t = 0; t < TT; ++t) {
    float* h1r = (t&1)? h1b : h1a;
    float* h1w = (t&1)? h1a : h1b;
    float* h2r = (t&1)? h2b : h2a;
    float* h2w = (t&1)? h2a : h2b;

    layer_phase(xbuf, h1r, wsT + (size_t)(i*2+0)*32768, h1w, c1, lds_b1, T, tid, Bbase, hugBase);
    gbar(bar, ep++, j);
    layer_phase(h1w, h2r, wsT + (size_t)(i*2+1)*32768, h2w, c2, lds_b2, T, tid, Bbase, hugBase);
    gbar(bar, ep++, j);
    fc2_phase(h2w, wsTf, ybuf, lds_bc, condY, T, tid, Bbase, hugBase);
    gbar(bar, ep++, j);
    // ---- phase D: WG handles batch row r = w: fc3, argmax, next x ----
    {
      if (tid < 512)
        lds_y[tid] = gld(ybuf + (size_t)((tid>>2)*256 + w)*4 + (tid&3));
      __syncthreads();
      int o = 0, kc = 0;
      bool active = false;
      if (tid < 512)        { o = tid & 31; kc = tid >> 5; active = true; }
      else if (tid < 528)   { o = 32;       kc = tid - 512; active = true; }
      if (active) {
        float p = 0.0f;
        const float* fw = fc3W + (size_t)o*HH + kc*32;
        #pragma unroll
        for (int k2 = 0; k2 < 32; ++k2) p += fw[k2] * lds_y[kc*32 + k2];
        part[o][kc] = p;
      }
      __syncthreads();
      float predv = -1e30f;
      if (tid < NOUT) {
        float s = fc3b[tid];
        #pragma unroll
        for (int kc2 = 0; kc2 < 16; ++kc2) s += part[tid][kc2];
        predv = s;
        out[(size_t)(w*TT + t)*NOUT + tid] = s;
      }
      if (tid < 64) {
        float v  = (tid < 32) ? predv : -1e30f;
        int  idx = tid;
        #pragma unroll
        for (int off = 32; off > 0; off >>= 1) {
          float ov = __shfl_xor(v, off);
          int   oi = __shfl_xor(idx, off);
          if (ov > v || (ov == v && oi < idx)) { v = ov; idx = oi; }
        }
        if (tid == 0) lds_act = idx;
      }
      __syncthreads();
      const int act = lds_act;
      if (tid < 512)
        gst(xbuf + (size_t)((tid>>2)*256 + w)*4 + (tid&3),
            (tid < HH-1) ? emb[(size_t)act*(HH-1) + tid] : 1.0f);
    }
    gbar(bar, ep++, j);
  }

  // ---- postprocess row w ----
  if (tid < TT) {
    const int s = tid;
    float* po = out + (size_t)(w*TT + s)*NOUT;
    float v[NOUT];
    #pragma unroll
    for (int o = 0; o < NOUT; ++o) v[o] = po[o];
    float m = v[0];
    #pragma unroll
    for (int o = 1; o < 32; ++o) m = fmaxf(m, v[o]);
    float sum = 0.0f;
    #pragma unroll
    for (int o = 0; o < 32; ++o) sum += expf(v[o] - m);
    float lse = m + logf(sum);
    #pragma unroll
    for (int o = 0; o < 32; ++o) po[o] = v[o] - lse;
    float d = v[32];
    float dm = d;
    #pragma unroll
    for (int off = 32; off > 0; off >>= 1) dm = fmaxf(dm, __shfl_xor(dm, off));
    float e = expf(d - dm);
    float es = e;
    #pragma unroll
    for (int off = 32; off > 0; off >>= 1) es += __shfl_xor(es, off);
    po[32] = e / es;
  }
}

extern "C" void kernel_launch(void* const* d_in, const int* in_sizes, int n_in,
                              void* d_out, int out_size, void* d_ws, size_t ws_size,
                              hipStream_t stream) {
  const float* h0   = (const float*)d_in[1];
  const float* c0   = (const float*)d_in[2];
  const float* cnd  = (const float*)d_in[3];
  const float* emb  = (const float*)d_in[4];
  const float* Wih  = (const float*)d_in[5];
  const float* Whh  = (const float*)d_in[6];
  const float* bih  = (const float*)d_in[7];
  const float* bhh  = (const float*)d_in[8];
  const float* fcW  = (const float*)d_in[9];
  const float* fcb  = (const float*)d_in[10];
  const float* fc2W = (const float*)d_in[11];
  const float* fc2b = (const float*)d_in[12];
  const float* fc3W = (const float*)d_in[13];
  const float* fc3b = (const float*)d_in[14];

  unsigned* bar = (unsigned*)d_ws;
  float* wsf = (float*)((char*)d_ws + 1024);
  float* wsT = wsf + 6*ABUF;

  (void)hipMemsetAsync(d_ws, 0, 1024, stream);

  hipLaunchKernelGGL(transpose_weights, dim3(64), dim3(256), 0, stream,
                     Wih, Whh, fc2W, wsT);
  hipLaunchKernelGGL(decoder_kernel, dim3(256), dim3(NTHR), 0, stream,
                     h0, c0, cnd, emb, bih, bhh, fcW, fcb,
                     fc2b, fc3W, fc3b, (float*)d_out, bar, wsf);
}

// Round 13
// 11634.043 us; speedup vs baseline: 1.1139x; 1.1139x over previous
//
#include <hip/hip_runtime.h>
#include <math.h>

#define BB   256
#define HH   512
#define TT   64
#define NOUT 33
#define CD   128
#define NTHR 1024
#define LOFF (4*HH*HH)

#define HUT  8          // hu per WG
#define BT   64         // batch cols per WG
#define ABUF 131072     // floats per activation buffer [k 512][b 256]
#define FC2OFF 4194304  // float offset of fc2 section inside wsT

typedef float f16v __attribute__((ext_vector_type(16)));
typedef const __attribute__((address_space(4))) float cfloat;
typedef const __attribute__((address_space(4))) f16v  cf16v;

__device__ __forceinline__ float sigm(float x)  { return 1.0f/(1.0f+expf(-x)); }
__device__ __forceinline__ float lrelu(float x) { return x >= 0.0f ? x : 0.01f*x; }

// memory-side coherent (cross-XCD) access, no fences needed (proven R11)
__device__ __forceinline__ float gld(const float* p) {
  return __hip_atomic_load(p, __ATOMIC_RELAXED, __HIP_MEMORY_SCOPE_AGENT);
}
__device__ __forceinline__ void gst(float* p, float v) {
  __hip_atomic_store(p, v, __ATOMIC_RELAXED, __HIP_MEMORY_SCOPE_AGENT);
}
__device__ __forceinline__ unsigned gldu(const unsigned* p) {
  return __hip_atomic_load(p, __ATOMIC_RELAXED, __HIP_MEMORY_SCOPE_AGENT);
}

// provably-uniform constant-AS pointer -> compiler emits s_load (proven R10/R11)
__device__ __forceinline__ cfloat* cptr(const float* p) {
  unsigned long long u = (unsigned long long)p;
  unsigned lo = __builtin_amdgcn_readfirstlane((unsigned)u);
  unsigned hi = __builtin_amdgcn_readfirstlane((unsigned)(u >> 32));
  return (cfloat*)((((unsigned long long)hi) << 32) | (unsigned long long)lo);
}

// j-group barrier: 64 WGs sharing a batch slice.
__device__ __forceinline__ void gbar(unsigned* bar, unsigned ep, int j) {
  __syncthreads();
  if (threadIdx.x == 0) {
    unsigned old = __hip_atomic_fetch_add(&bar[j*32], 1u, __ATOMIC_RELAXED, __HIP_MEMORY_SCOPE_AGENT);
    if (old == ep*64u + 63u)
      __hip_atomic_store(&bar[j*32+16], ep+1u, __ATOMIC_RELAXED, __HIP_MEMORY_SCOPE_AGENT);
    while (gldu(&bar[j*32+16]) < ep+1u) __builtin_amdgcn_s_sleep(1);
  }
  __syncthreads();
}

// ---- weight transpose pre-kernel ----
// layer section per i-slice: [l 2][a 2][o 4][kc 128][r8 8][kj 4]  (65536 floats)
// fc2 section per i-slice:   [kc 128][r8 8][kj 4]                 (4096 floats)
extern "C" __global__ void __launch_bounds__(256)
transpose_weights(const float* __restrict__ Wih, const float* __restrict__ Whh,
                  const float* __restrict__ fc2W, float* __restrict__ wsT)
{
  const int i = blockIdx.x, tid = threadIdx.x;
  #pragma unroll 1
  for (int idx = tid; idx < 65536; idx += 256) {
    int kj = idx & 3, r8 = (idx>>2)&7, kc = (idx>>5)&127, o = (idx>>12)&3, a = (idx>>14)&1, l = idx>>15;
    int hu = i*HUT + 2*o + (r8>>2), g = r8&3, k = kc*4+kj;
    const float* src = a ? Whh : Wih;
    wsT[(size_t)i*65536 + idx] = src[(size_t)l*LOFF + (size_t)(g*HH + hu)*HH + k];
  }
  #pragma unroll 1
  for (int idx = tid; idx < 4096; idx += 256) {
    int kj = idx & 3, r8 = (idx>>2)&7, kc = idx>>5;
    wsT[(size_t)FC2OFF + i*4096 + idx] = fc2W[(size_t)(i*HUT + r8)*HH + kc*4+kj];
  }
}

// ---- staging: wave wv owns 4 chunks; chunk = 4 k-rows x 64 b, COALESCED loads ----
__device__ __forceinline__ void stage_load(const float* src, int cBase, int wv, int bglob, float4* st) {
  #pragma unroll
  for (int q = 0; q < 4; ++q) {
    const float* p = src + (size_t)(cBase + wv*4 + q)*1024 + bglob;  // 4 k-rows = 1024 floats
    st[q].x = gld(p);
    st[q].y = gld(p + 256);
    st[q].z = gld(p + 512);
    st[q].w = gld(p + 768);
  }
  __builtin_amdgcn_sched_barrier(0);   // issue loads here; latency hides under consume
}
// LDS chunk layout [c][b][4k]: lane*16B -> conflict-free b128
__device__ __forceinline__ void stage_write(float* buf, int wv, int lane, const float4* st) {
  #pragma unroll
  for (int q = 0; q < 4; ++q)
    *(float4*)(buf + (wv*4+q)*256 + lane*4) = st[q];
}

// consume CNT chunks: per chunk, 4 k (LDS b128) x 8 gate-rows (SGPR weights)
template<int CNT>
__device__ __forceinline__ void consume(const float* buf, cfloat* wb, int cstart, int lane, float* acc) {
  #pragma unroll 1
  for (int m = 0; m < CNT; ++m) {
    int cL = cstart + m;
    float4 q = *(const float4*)(buf + cL*256 + lane*4);
    cf16v* wp = (cf16v*)(wb + (size_t)cL*32);
    f16v wA = wp[0], wB = wp[1];
    #pragma unroll
    for (int r = 0; r < 4; ++r) {
      acc[r]   += wA[r*4+0]*q.x + wA[r*4+1]*q.y + wA[r*4+2]*q.z + wA[r*4+3]*q.w;
      acc[4+r] += wB[r*4+0]*q.x + wB[r*4+1]*q.y + wB[r*4+2]*q.z + wB[r*4+3]*q.w;
    }
  }
}

// one LSTM layer phase: 4 half-tiles (x lo/hi, h lo/hi) pipelined via 2 LDS buffers
__device__ __forceinline__ void layer_phase(const float* xsrc, const float* hsrc,
    const float* wsTL, float* hdst, float& creg, const float* ldsb,
    float* T, int tid, int Bbase, int hugBase)
{
  const int lane = tid & 63, wv = tid >> 6;
  const int o = wv & 3, sub = wv >> 2;
  float* buf0 = T;
  float* buf1 = T + 16384;
  float acc[8];
  #pragma unroll
  for (int r = 0; r < 8; ++r) acc[r] = 0.f;
  cfloat* wx0 = cptr(wsTL + o*4096);
  cfloat* wx1 = cptr(wsTL + o*4096 + 2048);
  cfloat* wh0 = cptr(wsTL + 16384 + o*4096);
  cfloat* wh1 = cptr(wsTL + 16384 + o*4096 + 2048);

  float4 st[4];
  stage_load(xsrc, 0, wv, Bbase + lane, st);
  stage_write(buf0, wv, lane, st);
  __syncthreads();
  stage_load(xsrc, 64, wv, Bbase + lane, st);
  consume<16>(buf0, wx0, sub*16, lane, acc);
  stage_write(buf1, wv, lane, st);
  __syncthreads();
  stage_load(hsrc, 0, wv, Bbase + lane, st);
  consume<16>(buf1, wx1, sub*16, lane, acc);
  stage_write(buf0, wv, lane, st);
  __syncthreads();
  stage_load(hsrc, 64, wv, Bbase + lane, st);
  consume<16>(buf0, wh0, sub*16, lane, acc);
  stage_write(buf1, wv, lane, st);
  __syncthreads();
  consume<16>(buf1, wh1, sub*16, lane, acc);
  __syncthreads();
  #pragma unroll
  for (int r = 0; r < 8; ++r) T[(sub*32 + o*8 + r)*64 + lane] = acc[r];
  __syncthreads();
  if (tid < 512) {
    int hu = tid >> 6, b = tid & 63;
    float g[4];
    #pragma unroll
    for (int gg = 0; gg < 4; ++gg) {
      int gr = hu*4 + gg;
      float s = ldsb[gr];
      #pragma unroll
      for (int sb = 0; sb < 4; ++sb) s += T[(sb*32 + gr)*64 + b];
      g[gg] = s;
    }
    float ig = sigm(g[0]), fg = sigm(g[1]), gv = tanhf(g[2]), og = sigm(g[3]);
    float cn = fg*creg + ig*gv;
    creg = cn;
    gst(hdst + (size_t)(hugBase + hu)*256 + Bbase + b, og*tanhf(cn));  // coalesced rows
  }
  __syncthreads();
}

// fc2 phase: 2 half-tiles of h2, 8 output rows; writes TRANSPOSED yT[b][k] (scatter)
__device__ __forceinline__ void fc2_phase(const float* h2src, const float* wsTf,
    float* yT, const float* lds_bc, float condY, float* T, int tid, int Bbase, int hugBase)
{
  const int lane = tid & 63, wv = tid >> 6;
  float* buf0 = T;
  float* buf1 = T + 16384;
  float acc[8];
  #pragma unroll
  for (int r = 0; r < 8; ++r) acc[r] = 0.f;
  cfloat* w0 = cptr(wsTf);
  cfloat* w1 = cptr(wsTf + 2048);

  float4 st[4];
  stage_load(h2src, 0, wv, Bbase + lane, st);
  stage_write(buf0, wv, lane, st);
  __syncthreads();
  stage_load(h2src, 64, wv, Bbase + lane, st);
  consume<4>(buf0, w0, wv*4, lane, acc);
  stage_write(buf1, wv, lane, st);
  __syncthreads();
  consume<4>(buf1, w1, wv*4, lane, acc);
  __syncthreads();
  #pragma unroll
  for (int r = 0; r < 8; ++r) T[(wv*8 + r)*64 + lane] = acc[r];
  __syncthreads();
  if (tid < 512) {
    int row = tid >> 6, b = tid & 63;
    float s = lds_bc[row] + condY;
    #pragma unroll
    for (int w16 = 0; w16 < 16; ++w16) s += T[(w16*8 + row)*64 + b];
    gst(yT + (size_t)(Bbase + b)*HH + hugBase + row, lrelu(s));  // scatter store
  }
  __syncthreads();
}

extern "C" __global__ void __launch_bounds__(NTHR)
decoder_kernel(const float* __restrict__ h0, const float* __restrict__ c0,
               const float* __restrict__ conds, const float* __restrict__ emb,
               const float* __restrict__ bih, const float* __restrict__ bhh,
               const float* __restrict__ fcW, const float* __restrict__ fcb,
               const float* __restrict__ fc2b, const float* __restrict__ fc3W,
               const float* __restrict__ fc3b,
               float* __restrict__ out, unsigned* bar, float* wsf)
{
  const int w = blockIdx.x;
  const int i = w & 63, j = w >> 6;     // 4 j's per i share an XCD -> weights L2-local
  const int tid = threadIdx.x;
  const int lane = tid & 63, wv = tid >> 6;
  const int Bbase = j*BT;
  const int hugBase = i*HUT;

  float* xbuf = wsf;                    // [k][b]
  float* h1a = wsf + 1*ABUF;
  float* h1b = wsf + 2*ABUF;
  float* h2a = wsf + 3*ABUF;
  float* h2b = wsf + 4*ABUF;
  float* yT   = wsf + 5*ABUF;           // [b][k] transposed
  const float* wsT  = wsf + 6*ABUF;
  const float* wsTf = wsT + FC2OFF + i*4096;

  __shared__ float4 T4[8192];           // 128KB staging + partial overlay
  float* T = (float*)T4;
  __shared__ float lds_y[HH];
  __shared__ float part[NOUT][17];
  __shared__ float lds_b1[32], lds_b2[32], lds_bc[8];
  __shared__ int   lds_act;

  if (tid < 32) {
    int hu = hugBase + (tid>>2), g = tid&3;
    lds_b1[tid] = bih[g*HH+hu] + bhh[g*HH+hu];
    lds_b2[tid] = bih[4*HH + g*HH+hu] + bhh[4*HH + g*HH+hu];
  }
  if (tid < 8) lds_bc[tid] = fc2b[hugBase + tid];

  // ---- state init ([k][b] layouts, sc stores) ----
  float c1 = 0.f, c2 = 0.f;
  if (tid < 512) {
    int hu = tid>>6, b = tid&63;
    int hug = hugBase + hu, bg = Bbase + b;
    c1 = c0[(size_t)bg*HH + hug];
    c2 = c0[(size_t)(BB+bg)*HH + hug];
    gst(h1a + (size_t)hug*256 + bg, h0[(size_t)bg*HH+hug]);
    gst(h2a + (size_t)hug*256 + bg, h0[(size_t)(BB+bg)*HH+hug]);
  }
  #pragma unroll 1
  for (int it = 0; it < 32; ++it) {     // x0 = [emb[SOS=0] | dur=0]
    int idx = it*1024 + tid;
    int b = idx & 63, k = idx >> 6;
    gst(xbuf + (size_t)k*256 + Bbase + b, (k < HH-1) ? emb[k] : 0.0f);
  }

  // ---- condb tile -> LDS chunks [kc][b][4] -> condY register ----
  {
    int b = tid&63, kcg = tid>>6;
    const float* crow = conds + (size_t)(Bbase+b)*CD;
    #pragma unroll 1
    for (int it = 0; it < 8; ++it) {
      int kc = kcg + it*16;
      float4 v;
      #pragma unroll
      for (int kj = 0; kj < 4; ++kj) {
        int k = kc*4+kj;
        const float* fr = fcW + (size_t)k*CD;
        float s = fcb[k];
        #pragma unroll 4
        for (int q = 0; q < CD; q += 4)
          s += fr[q]*crow[q] + fr[q+1]*crow[q+1] + fr[q+2]*crow[q+2] + fr[q+3]*crow[q+3];
        ((float*)&v)[kj] = lrelu(s);
      }
      *(float4*)(T + kc*256 + b*4) = v;
    }
  }
  __syncthreads();
  float condY = 0.f;
  {
    float accy[8];
    #pragma unroll
    for (int r = 0; r < 8; ++r) accy[r] = 0.f;
    consume<8>(T, cptr(wsTf), wv*8, lane, accy);
    __syncthreads();
    #pragma unroll
    for (int r = 0; r < 8; ++r) T[(wv*8+r)*64 + lane] = accy[r];
    __syncthreads();
    if (tid < 512) {
      int row = tid>>6, b = tid&63;
      #pragma unroll
      for (int w16 = 0; w16 < 16; ++w16) condY += T[(w16*8+row)*64 + b];
    }
  }

  unsigned ep = 0;
  gbar(bar, ep++, j);

  for (int t = 0; t < TT; ++t) {
    float* h1r = (t&1)? h1b : h1a;
    float* h1w = (t&1)? h1a : h1b;
    float* h2r = (t&1)? h2b : h2a;
    float* h2w = (t&1)? h2a : h2b;
    (void)h1r; (void)h2r;

    layer_phase(xbuf, h1r, wsT + (size_t)(i*2+0)*32768, h1w, c1, lds_b1, T, tid, Bbase, hugBase);
    gbar(bar, ep++, j);
    layer_phase(h1w, h2r, wsT + (size_t)(i*2+1)*32768, h2w, c2, lds_b2, T, tid, Bbase, hugBase);
    gbar(bar, ep++, j);
    fc2_phase(h2w, wsTf, yT, lds_bc, condY, T, tid, Bbase, hugBase);
    gbar(bar, ep++, j);
    // ---- phase D: WG handles batch row w: fc3, argmax, next x ----
    {
      if (tid < 512) lds_y[tid] = gld(yT + (size_t)w*HH + tid);   // coalesced
      __syncthreads();
      int o = 0, kc = 0;
      bool active = false;
      if (tid < 512)        { o = tid & 31; kc = tid >> 5; active = true; }
      else if (tid < 528)   { o = 32;       kc = tid - 512; active = true; }
      if (active) {
        float p = 0.0f;
        const float* fw = fc3W + (size_t)o*HH + kc*32;
        #pragma unroll
        for (int k2 = 0; k2 < 32; ++k2) p += fw[k2] * lds_y[kc*32 + k2];
        part[o][kc] = p;
      }
      __syncthreads();
      float predv = -1e30f;
      if (tid < NOUT) {
        float s = fc3b[tid];
        #pragma unroll
        for (int kc2 = 0; kc2 < 16; ++kc2) s += part[tid][kc2];
        predv = s;
        out[(size_t)(w*TT + t)*NOUT + tid] = s;
      }
      if (tid < 64) {
        float v  = (tid < 32) ? predv : -1e30f;
        int  idx = tid;
        #pragma unroll
        for (int off = 32; off > 0; off >>= 1) {
          float ov = __shfl_xor(v, off);
          int   oi = __shfl_xor(idx, off);
          if (ov > v || (ov == v && oi < idx)) { v = ov; idx = oi; }
        }
        if (tid == 0) lds_act = idx;
      }
      __syncthreads();
      const int act = lds_act;
      if (tid < 512)
        gst(xbuf + (size_t)tid*256 + w, (tid < HH-1) ? emb[(size_t)act*(HH-1) + tid] : 1.0f);
    }
    gbar(bar, ep++, j);
  }

  // ---- postprocess row w ----
  if (tid < TT) {
    const int s = tid;
    float* po = out + (size_t)(w*TT + s)*NOUT;
    float v[NOUT];
    #pragma unroll
    for (int o = 0; o < NOUT; ++o) v[o] = po[o];
    float m = v[0];
    #pragma unroll
    for (int o = 1; o < 32; ++o) m = fmaxf(m, v[o]);
    float sum = 0.0f;
    #pragma unroll
    for (int o = 0; o < 32; ++o) sum += expf(v[o] - m);
    float lse = m + logf(sum);
    #pragma unroll
    for (int o = 0; o < 32; ++o) po[o] = v[o] - lse;
    float d = v[32];
    float dm = d;
    #pragma unroll
    for (int off = 32; off > 0; off >>= 1) dm = fmaxf(dm, __shfl_xor(dm, off));
    float e = expf(d - dm);
    float es = e;
    #pragma unroll
    for (int off = 32; off > 0; off >>= 1) es += __shfl_xor(es, off);
    po[32] = e / es;
  }
}

extern "C" void kernel_launch(void* const* d_in, const int* in_sizes, int n_in,
                              void* d_out, int out_size, void* d_ws, size_t ws_size,
                              hipStream_t stream) {
  const float* h0   = (const float*)d_in[1];
  const float* c0   = (const float*)d_in[2];
  const float* cnd  = (const float*)d_in[3];
  const float* emb  = (const float*)d_in[4];
  const float* Wih  = (const float*)d_in[5];
  const float* Whh  = (const float*)d_in[6];
  const float* bih  = (const float*)d_in[7];
  const float* bhh  = (const float*)d_in[8];
  const float* fcW  = (const float*)d_in[9];
  const float* fcb  = (const float*)d_in[10];
  const float* fc2W = (const float*)d_in[11];
  const float* fc2b = (const float*)d_in[12];
  const float* fc3W = (const float*)d_in[13];
  const float* fc3b = (const float*)d_in[14];

  unsigned* bar = (unsigned*)d_ws;
  float* wsf = (float*)((char*)d_ws + 1024);
  float* wsT = wsf + 6*ABUF;

  (void)hipMemsetAsync(d_ws, 0, 1024, stream);

  hipLaunchKernelGGL(transpose_weights, dim3(64), dim3(256), 0, stream,
                     Wih, Whh, fc2W, wsT);
  hipLaunchKernelGGL(decoder_kernel, dim3(256), dim3(NTHR), 0, stream,
                     h0, c0, cnd, emb, bih, bhh, fcW, fcb,
                     fc2b, fc3W, fc3b, (float*)d_out, bar, wsf);
}

// Round 14
// 4567.353 us; speedup vs baseline: 2.8373x; 2.5472x over previous
//
#include <hip/hip_runtime.h>
#include <math.h>

#define BB   256
#define HH   512
#define TT   64
#define NOUT 33
#define CD   128
#define NTHR 1024
#define NWG  256
#define LOFF (4*HH*HH)
#define SZ   (HH*BB)            // 131072 floats
#define FC2OFF 4194304          // 128 i-slices * 32768 floats

typedef float f16v __attribute__((ext_vector_type(16)));
typedef const __attribute__((address_space(4))) float cfloat;
typedef const __attribute__((address_space(4))) f16v  cf16v;

__device__ __forceinline__ float sigm(float x)  { return 1.0f/(1.0f+expf(-x)); }
__device__ __forceinline__ float lrelu(float x) { return x >= 0.0f ? x : 0.01f*x; }

// memory-side coherent access (cross-XCD safe without fences; proven R11)
__device__ __forceinline__ float gld(const float* p) {
  return __hip_atomic_load(p, __ATOMIC_RELAXED, __HIP_MEMORY_SCOPE_AGENT);
}
__device__ __forceinline__ float2 gld2(const float* p) {
  unsigned long long v = __hip_atomic_load((const unsigned long long*)p,
                                           __ATOMIC_RELAXED, __HIP_MEMORY_SCOPE_AGENT);
  union { unsigned long long u; float2 f; } c; c.u = v; return c.f;
}
__device__ __forceinline__ void gst(float* p, float v) {
  __hip_atomic_store(p, v, __ATOMIC_RELAXED, __HIP_MEMORY_SCOPE_AGENT);
}
__device__ __forceinline__ unsigned gldu(const unsigned* p) {
  return __hip_atomic_load(p, __ATOMIC_RELAXED, __HIP_MEMORY_SCOPE_AGENT);
}

// provably-uniform constant-AS pointer -> s_load scalar stream (proven R10/R11)
__device__ __forceinline__ cfloat* cptr(const float* p) {
  unsigned long long u = (unsigned long long)p;
  unsigned lo = __builtin_amdgcn_readfirstlane((unsigned)u);
  unsigned hi = __builtin_amdgcn_readfirstlane((unsigned)(u >> 32));
  return (cfloat*)((((unsigned long long)hi) << 32) | (unsigned long long)lo);
}

// Monotonic 2-level grid barrier (8 groups of 32 -> global 8). fence only at init.
__device__ __forceinline__ void gbar(unsigned* bar, unsigned ep, int grp, bool fence) {
  __syncthreads();
  if (threadIdx.x == 0) {
    if (fence) __builtin_amdgcn_fence(__ATOMIC_RELEASE, "agent");
    unsigned old = __hip_atomic_fetch_add(&bar[grp*16], 1u, __ATOMIC_RELAXED, __HIP_MEMORY_SCOPE_AGENT);
    if (old == ep*32u + 31u) {
      unsigned o2 = __hip_atomic_fetch_add(&bar[128], 1u, __ATOMIC_RELAXED, __HIP_MEMORY_SCOPE_AGENT);
      if (o2 == ep*8u + 7u)
        __hip_atomic_store(&bar[144], ep+1u, __ATOMIC_RELAXED, __HIP_MEMORY_SCOPE_AGENT);
    }
    while (gldu(&bar[144]) < ep+1u) __builtin_amdgcn_s_sleep(1);
    if (fence) __builtin_amdgcn_fence(__ATOMIC_ACQUIRE, "agent");
  }
  __syncthreads();
}

// ---- weight transpose ----
// LSTM per i: [l 2][rh 2][k 512][16] ; slot = [Wi r0..7 | Wh r0..7], r = u*4+g, hu = i*4+rh*2+u
// fc2 per i:  [k 512][4 rows]
extern "C" __global__ void __launch_bounds__(256)
transpose_weights(const float* __restrict__ Wih, const float* __restrict__ Whh,
                  const float* __restrict__ fc2W, float* __restrict__ wsT)
{
  const int i = blockIdx.x, tid = threadIdx.x;
  float* dst = wsT + (size_t)i*32768;
  #pragma unroll 1
  for (int idx = tid; idx < 32768; idx += 256) {
    int slot = idx & 15, k = (idx>>4)&511, rh = (idx>>13)&1, l = (idx>>14)&1;
    int a = slot>>3, r = slot&7, u = r>>2, g = r&3;
    int hu = i*4 + rh*2 + u;
    const float* src = a ? Whh : Wih;
    dst[idx] = src[(size_t)l*LOFF + (size_t)(g*HH+hu)*HH + k];
  }
  float* dstf = wsT + FC2OFF + (size_t)i*2048;
  #pragma unroll 1
  for (int idx = tid; idx < 2048; idx += 256) {
    int r = idx & 3, k = idx >> 2;
    dstf[idx] = fc2W[(size_t)(i*4+r)*HH + k];
  }
}

// LSTM layer phase. Wave (ks 8, rh 2): k-slice 64, 8 gate-rows (rh half of 16),
// 128 b-cols (2 adjacent per lane, packed float2 sc loads, prefetch depth 2).
__device__ __forceinline__ void lstm_phase(const float* __restrict__ wTl,
    const float* __restrict__ bias, float* __restrict__ red,
    const float* __restrict__ xsrc, const float* __restrict__ hsrc,
    float* __restrict__ hdst, float& creg, int i, int j, int tid)
{
  const int lane = tid & 63, wvid = tid >> 6;
  const int rh = wvid & 1, ks = wvid >> 1;
  cf16v* wp = (cf16v*)cptr(wTl + ((size_t)rh*512 + ks*64)*16);
  const int bo = j*128 + 2*lane;
  const float* xp = xsrc + (size_t)(ks*64)*BB + bo;
  const float* hp = hsrc + (size_t)(ks*64)*BB + bo;

  float acc[16];
  #pragma unroll
  for (int r = 0; r < 16; ++r) acc[r] = 0.f;

  float2 qx[2], qh[2], px[2], ph[2], rx[2], rhb[2];
  #pragma unroll
  for (int kk = 0; kk < 2; ++kk) { qx[kk]=gld2(xp+kk*BB);     qh[kk]=gld2(hp+kk*BB); }
  #pragma unroll
  for (int kk = 0; kk < 2; ++kk) { px[kk]=gld2(xp+(2+kk)*BB); ph[kk]=gld2(hp+(2+kk)*BB); }

  #pragma unroll 1
  for (int g = 0; g < 32; ++g) {
    if (g+2 < 32) {
      #pragma unroll
      for (int kk = 0; kk < 2; ++kk) {
        rx[kk]  = gld2(xp + (g*2+4+kk)*BB);
        rhb[kk] = gld2(hp + (g*2+4+kk)*BB);
      }
    }
    #pragma unroll
    for (int kk = 0; kk < 2; ++kk) {
      f16v w = wp[g*2+kk];
      float2 xv = qx[kk], hv = qh[kk];
      #pragma unroll
      for (int r = 0; r < 8; ++r) {
        acc[r*2+0] += w[r]*xv.x + w[8+r]*hv.x;
        acc[r*2+1] += w[r]*xv.y + w[8+r]*hv.y;
      }
    }
    #pragma unroll
    for (int kk = 0; kk < 2; ++kk) {
      qx[kk]=px[kk]; qh[kk]=ph[kk]; px[kk]=rx[kk]; ph[kk]=rhb[kk];
    }
  }
  #pragma unroll
  for (int r = 0; r < 8; ++r)
    *(float2*)(red + (size_t)(ks*16 + rh*8 + r)*128 + 2*lane) = make_float2(acc[r*2], acc[r*2+1]);
  __syncthreads();
  if (tid < 512) {
    const int lhu = tid >> 7, b = tid & 127;
    float g4[4];
    #pragma unroll
    for (int gg = 0; gg < 4; ++gg) {
      float s = bias[lhu*4+gg];
      #pragma unroll
      for (int q = 0; q < 8; ++q) s += red[(q*16 + lhu*4+gg)*128 + b];
      g4[gg] = s;
    }
    float ig=sigm(g4[0]), fg=sigm(g4[1]), gv=tanhf(g4[2]), og=sigm(g4[3]);
    float cn = fg*creg + ig*gv;
    creg = cn;
    gst(hdst + (size_t)(i*4+lhu)*BB + j*128 + b, og*tanhf(cn));
  }
}

// fc2 phase: wave ks2 (16): k-slice 32, 4 rows, 128 b (2/lane).
__device__ __forceinline__ void fc2_phase(const float* __restrict__ h2src,
    const float* __restrict__ wsTf, float* __restrict__ yb,
    const float* lds_bc, const float* condY_l, float* __restrict__ red,
    int i, int j, int tid)
{
  const int lane = tid & 63, ks2 = tid >> 6;
  cf16v* wp = (cf16v*)cptr(wsTf + (size_t)ks2*128);
  const int bo = j*128 + 2*lane;
  const float* hp = h2src + (size_t)(ks2*32)*BB + bo;
  float acc[8];
  #pragma unroll
  for (int r = 0; r < 8; ++r) acc[r] = 0.f;
  float2 qh[4], ph[4];
  #pragma unroll
  for (int kk = 0; kk < 4; ++kk) qh[kk] = gld2(hp + kk*BB);
  #pragma unroll 1
  for (int g = 0; g < 8; ++g) {
    if (g+1 < 8) {
      #pragma unroll
      for (int kk = 0; kk < 4; ++kk) ph[kk] = gld2(hp + (g*4+4+kk)*BB);
    }
    f16v w = wp[g];
    #pragma unroll
    for (int kk = 0; kk < 4; ++kk) {
      float2 hv = qh[kk];
      #pragma unroll
      for (int r = 0; r < 4; ++r) {
        acc[r*2+0] += w[kk*4+r]*hv.x;
        acc[r*2+1] += w[kk*4+r]*hv.y;
      }
    }
    #pragma unroll
    for (int kk = 0; kk < 4; ++kk) qh[kk] = ph[kk];
  }
  #pragma unroll
  for (int r = 0; r < 4; ++r)
    *(float2*)(red + (size_t)(ks2*4+r)*128 + 2*lane) = make_float2(acc[r*2], acc[r*2+1]);
  __syncthreads();
  if (tid < 512) {
    int r = tid >> 7, b = tid & 127;
    float s = lds_bc[r] + condY_l[r*128+b];
    #pragma unroll
    for (int q = 0; q < 16; ++q) s += red[(q*4+r)*128 + b];
    gst(yb + (size_t)(i*4+r)*BB + j*128 + b, lrelu(s));
  }
}

extern "C" __global__ void __launch_bounds__(NTHR)
decoder_kernel(const float* __restrict__ h0, const float* __restrict__ c0,
               const float* __restrict__ conds, const float* __restrict__ emb,
               const float* __restrict__ wsTW, const float* __restrict__ bih,
               const float* __restrict__ bhh, const float* __restrict__ fcW,
               const float* __restrict__ fcb, const float* __restrict__ fc2W,
               const float* __restrict__ fc2b, const float* __restrict__ fc3W,
               const float* __restrict__ fc3b,
               float* __restrict__ out, unsigned* bar, float* wsf)
{
  const int w = blockIdx.x;
  const int i = w & 127, j = w >> 7;   // w and w+128 share i -> same XCD -> weights L2-local
  const int grp = w & 7;
  const int tid = threadIdx.x;

  float* xbuf  = wsf;
  float* h1a = wsf + 1*SZ;  float* h1b = wsf + 2*SZ;
  float* h2a = wsf + 3*SZ;  float* h2b = wsf + 4*SZ;
  float* yb  = wsf + 5*SZ;
  float* condb = wsf + 6*SZ;
  const float* wTi  = wsTW + (size_t)i*32768;
  const float* wsTf = wsTW + FC2OFF + (size_t)i*2048;

  __shared__ float red[16384];        // 64KB
  __shared__ float lds_y[HH];
  __shared__ float part[NOUT][17];
  __shared__ float condY_l[512];
  __shared__ float lds_b1[16], lds_b2[16], lds_bc[4];
  __shared__ int   lds_act;
  __shared__ float lds_pad[3072];     // total LDS > 80KB -> exactly 1 WG/CU
  if (tid == 0) ((volatile float*)lds_pad)[0] = 0.f;

  if (tid < 16) {
    int u2 = tid >> 2, g = tid & 3;
    int hu = i*4 + u2;
    lds_b1[tid] = bih[g*HH+hu] + bhh[g*HH+hu];
    lds_b2[tid] = bih[4*HH + g*HH+hu] + bhh[4*HH + g*HH+hu];
  }
  if (tid < 4) lds_bc[tid] = fc2b[i*4 + tid];

  // ---- init: exchanged state (normal stores; published by the one fenced barrier) ----
  {
    int u = tid >> 8, b = tid & 255;
    int hug = i*4 + u;
    h1a[(size_t)hug*BB + b] = h0[(size_t)b*HH + hug];
    h2a[(size_t)hug*BB + b] = h0[(size_t)(BB+b)*HH + hug];
    xbuf[(size_t)hug*BB + b] = (hug < HH-1) ? emb[hug] : 0.0f;   // emb[SOS=0], dur=0
    const float* crow = conds + (size_t)b*CD;
    cfloat* fr = cptr(fcW + (size_t)hug*CD);
    float s = fcb[hug];
    #pragma unroll 4
    for (int q = 0; q < CD; q += 4)
      s += fr[q]*crow[q] + fr[q+1]*crow[q+1] + fr[q+2]*crow[q+2] + fr[q+3]*crow[q+3];
    condb[(size_t)hug*BB + b] = lrelu(s);
  }
  float c1 = 0.f, c2 = 0.f;
  if (tid < 512) {
    int lhu = tid >> 7, b = tid & 127;
    int hug = i*4 + lhu, bg = j*128 + b;
    c1 = c0[(size_t)bg*HH + hug];
    c2 = c0[(size_t)(BB+bg)*HH + hug];
  }
  unsigned ep = 0;
  gbar(bar, ep++, grp, true);   // publish init (release+acquire once; weights not yet hot)

  // condY_l[r][b]: cond-branch through fc2, WG-private in LDS
  if (tid < 512) {
    int r = tid >> 7, b = tid & 127, bg = j*128 + b;
    cfloat* wr = cptr(fc2W + (size_t)(i*4+r)*HH);
    float s = 0.f;
    #pragma unroll 4
    for (int k = 0; k < HH; ++k) s += wr[k]*condb[(size_t)k*BB + bg];
    condY_l[r*128 + b] = s;
  }
  __syncthreads();

  for (int t = 0; t < TT; ++t) {
    float* h1r = (t&1) ? h1b : h1a;  float* h1w = (t&1) ? h1a : h1b;
    float* h2r = (t&1) ? h2b : h2a;  float* h2w = (t&1) ? h2a : h2b;

    lstm_phase(wTi,         lds_b1, red, xbuf, h1r, h1w, c1, i, j, tid);
    gbar(bar, ep++, grp, false);
    lstm_phase(wTi + 16384, lds_b2, red, h1w, h2r, h2w, c2, i, j, tid);
    gbar(bar, ep++, grp, false);
    fc2_phase(h2w, wsTf, yb, lds_bc, condY_l, red, i, j, tid);
    gbar(bar, ep++, grp, false);
    // ---- phase D: WG w owns batch row w: fc3, argmax, next x ----
    {
      if (tid < 512) lds_y[tid] = gld(yb + (size_t)tid*BB + w);
      __syncthreads();
      int o = 0, kc = 0;
      bool active = false;
      if (tid < 512)      { o = tid & 31; kc = tid >> 5; active = true; }
      else if (tid < 528) { o = 32;       kc = tid - 512; active = true; }
      if (active) {
        float p = 0.f;
        const float* fw = fc3W + (size_t)o*HH + kc*32;
        #pragma unroll
        for (int k2 = 0; k2 < 32; ++k2) p += fw[k2] * lds_y[kc*32 + k2];
        part[o][kc] = p;
      }
      __syncthreads();
      float predv = -1e30f;
      if (tid < NOUT) {
        float s = fc3b[tid];
        #pragma unroll
        for (int kc2 = 0; kc2 < 16; ++kc2) s += part[tid][kc2];
        predv = s;
        out[(size_t)(w*TT + t)*NOUT + tid] = s;
      }
      if (tid < 64) {
        float v  = (tid < 32) ? predv : -1e30f;
        int  idx = tid;
        #pragma unroll
        for (int off = 32; off > 0; off >>= 1) {
          float ov = __shfl_xor(v, off);
          int   oi = __shfl_xor(idx, off);
          if (ov > v || (ov == v && oi < idx)) { v = ov; idx = oi; }
        }
        if (tid == 0) lds_act = idx;
      }
      __syncthreads();
      const int act = lds_act;
      if (tid < 512)
        gst(xbuf + (size_t)tid*BB + w, (tid < HH-1) ? emb[(size_t)act*(HH-1) + tid] : 1.0f);
    }
    gbar(bar, ep++, grp, false);
  }

  // ---- postprocess row w ----
  if (tid < TT) {
    const int s = tid;
    float* po = out + (size_t)(w*TT + s)*NOUT;
    float v[NOUT];
    #pragma unroll
    for (int o = 0; o < NOUT; ++o) v[o] = po[o];
    float m = v[0];
    #pragma unroll
    for (int o = 1; o < 32; ++o) m = fmaxf(m, v[o]);
    float sum = 0.f;
    #pragma unroll
    for (int o = 0; o < 32; ++o) sum += expf(v[o] - m);
    float lse = m + logf(sum);
    #pragma unroll
    for (int o = 0; o < 32; ++o) po[o] = v[o] - lse;
    float d = v[32];
    float dm = d;
    #pragma unroll
    for (int off = 32; off > 0; off >>= 1) dm = fmaxf(dm, __shfl_xor(dm, off));
    float e = expf(d - dm);
    float es = e;
    #pragma unroll
    for (int off = 32; off > 0; off >>= 1) es += __shfl_xor(es, off);
    po[32] = e / es;
  }
}

extern "C" void kernel_launch(void* const* d_in, const int* in_sizes, int n_in,
                              void* d_out, int out_size, void* d_ws, size_t ws_size,
                              hipStream_t stream) {
  const float* h0   = (const float*)d_in[1];
  const float* c0   = (const float*)d_in[2];
  const float* cnd  = (const float*)d_in[3];
  const float* emb  = (const float*)d_in[4];
  const float* Wih  = (const float*)d_in[5];
  const float* Whh  = (const float*)d_in[6];
  const float* bih  = (const float*)d_in[7];
  const float* bhh  = (const float*)d_in[8];
  const float* fcW  = (const float*)d_in[9];
  const float* fcb  = (const float*)d_in[10];
  const float* fc2W = (const float*)d_in[11];
  const float* fc2b = (const float*)d_in[12];
  const float* fc3W = (const float*)d_in[13];
  const float* fc3b = (const float*)d_in[14];

  unsigned* bar = (unsigned*)d_ws;
  float* wsf = (float*)((char*)d_ws + 1024);
  float* wsT = wsf + 7*SZ;

  (void)hipMemsetAsync(d_ws, 0, 1024, stream);

  hipLaunchKernelGGL(transpose_weights, dim3(128), dim3(256), 0, stream,
                     Wih, Whh, fc2W, wsT);
  hipLaunchKernelGGL(decoder_kernel, dim3(NWG), dim3(NTHR), 0, stream,
                     h0, c0, cnd, emb, wsT, bih, bhh, fcW, fcb,
                     fc2W, fc2b, fc3W, fc3b, (float*)d_out, bar, wsf);
}

// Round 15
// 4062.014 us; speedup vs baseline: 3.1903x; 1.1244x over previous
//
#include <hip/hip_runtime.h>
#include <math.h>

#define BB   256
#define HH   512
#define TT   64
#define NOUT 33
#define CD   128
#define NTHR 1024
#define NWG  256
#define LOFF (4*HH*HH)
#define SZ   (HH*BB)            // 131072 floats
#define FC2OFF 4194304          // 128 i-slices * 32768 floats

typedef float f16v __attribute__((ext_vector_type(16)));
typedef float f8v  __attribute__((ext_vector_type(8)));
typedef const __attribute__((address_space(4))) float cfloat;
typedef const __attribute__((address_space(4))) f16v  cf16v;
typedef const __attribute__((address_space(4))) f8v   cf8v;

__device__ __forceinline__ float sigm(float x)  { return 1.0f/(1.0f+expf(-x)); }
__device__ __forceinline__ float lrelu(float x) { return x >= 0.0f ? x : 0.01f*x; }

// memory-side coherent access (cross-XCD safe without fences; proven R11-R14)
__device__ __forceinline__ float gld(const float* p) {
  return __hip_atomic_load(p, __ATOMIC_RELAXED, __HIP_MEMORY_SCOPE_AGENT);
}
__device__ __forceinline__ float2 gld2(const float* p) {
  unsigned long long v = __hip_atomic_load((const unsigned long long*)p,
                                           __ATOMIC_RELAXED, __HIP_MEMORY_SCOPE_AGENT);
  union { unsigned long long u; float2 f; } c; c.u = v; return c.f;
}
__device__ __forceinline__ void gst(float* p, float v) {
  __hip_atomic_store(p, v, __ATOMIC_RELAXED, __HIP_MEMORY_SCOPE_AGENT);
}
__device__ __forceinline__ unsigned gldu(const unsigned* p) {
  return __hip_atomic_load(p, __ATOMIC_RELAXED, __HIP_MEMORY_SCOPE_AGENT);
}

// provably-uniform constant-AS pointer -> s_load scalar stream (proven R10+)
__device__ __forceinline__ cfloat* cptr(const float* p) {
  unsigned long long u = (unsigned long long)p;
  unsigned lo = __builtin_amdgcn_readfirstlane((unsigned)u);
  unsigned hi = __builtin_amdgcn_readfirstlane((unsigned)(u >> 32));
  return (cfloat*)((((unsigned long long)hi) << 32) | (unsigned long long)lo);
}

// Monotonic 2-level grid barrier (8 groups of 32 -> global 8). fence only at init.
__device__ __forceinline__ void gbar(unsigned* bar, unsigned ep, int grp, bool fence) {
  __syncthreads();
  if (threadIdx.x == 0) {
    if (fence) __builtin_amdgcn_fence(__ATOMIC_RELEASE, "agent");
    unsigned old = __hip_atomic_fetch_add(&bar[grp*16], 1u, __ATOMIC_RELAXED, __HIP_MEMORY_SCOPE_AGENT);
    if (old == ep*32u + 31u) {
      unsigned o2 = __hip_atomic_fetch_add(&bar[128], 1u, __ATOMIC_RELAXED, __HIP_MEMORY_SCOPE_AGENT);
      if (o2 == ep*8u + 7u)
        __hip_atomic_store(&bar[144], ep+1u, __ATOMIC_RELAXED, __HIP_MEMORY_SCOPE_AGENT);
    }
    while (gldu(&bar[144]) < ep+1u) __builtin_amdgcn_s_sleep(1);
    if (fence) __builtin_amdgcn_fence(__ATOMIC_ACQUIRE, "agent");
  }
  __syncthreads();
}

// ---- weight transpose ----
// LSTM per i: [l 2][k 512][32] ; 32 = [Wi r0..15 | Wh r0..15], r = u*4+g, hu = i*4+u
// fc2 per i:  [k 512][4 rows]
extern "C" __global__ void __launch_bounds__(256)
transpose_weights(const float* __restrict__ Wih, const float* __restrict__ Whh,
                  const float* __restrict__ fc2W, float* __restrict__ wsT)
{
  const int i = blockIdx.x, tid = threadIdx.x;
  float* dst = wsT + (size_t)i*32768;
  #pragma unroll 1
  for (int idx = tid; idx < 32768; idx += 256) {
    int slot = idx & 31, k = (idx>>5)&511, l = idx>>14;
    int a = slot>>4, r = slot&15, u = r>>2, g = r&3;
    int hu = i*4 + u;
    const float* src = a ? Whh : Wih;
    dst[idx] = src[(size_t)l*LOFF + (size_t)(g*HH+hu)*HH + k];
  }
  float* dstf = wsT + FC2OFF + (size_t)i*2048;
  #pragma unroll 1
  for (int idx = tid; idx < 2048; idx += 256) {
    int r = idx & 3, k = idx >> 2;
    dstf[idx] = fc2W[(size_t)(i*4+r)*HH + k];
  }
}

// LSTM layer phase. Wave ks (16): 32-k slice, ALL 16 gate rows, 128 b (2/lane).
// No duplicated activation reads; 64 FMA per k vs 2 packed loads.
__device__ __forceinline__ void lstm_phase(const float* __restrict__ wTl,
    const float* __restrict__ bias, float* __restrict__ red,
    const float* __restrict__ xsrc, const float* __restrict__ hsrc,
    float* __restrict__ hdst, float& creg, int i, int j, int tid)
{
  const int lane = tid & 63, ks = tid >> 6;
  cf16v* wp = (cf16v*)cptr(wTl + (size_t)(ks*32)*32);
  const int bo = j*128 + 2*lane;
  const float* xp = xsrc + (size_t)(ks*32)*BB + bo;
  const float* hp = hsrc + (size_t)(ks*32)*BB + bo;

  float acc[32];
  #pragma unroll
  for (int r = 0; r < 32; ++r) acc[r] = 0.f;

  float2 qx0, qh0, qx1, qh1, nx0, nh0, nx1, nh1;
  qx0 = gld2(xp);      qh0 = gld2(hp);
  qx1 = gld2(xp + BB); qh1 = gld2(hp + BB);

  #pragma unroll 1
  for (int it = 0; it < 16; ++it) {
    if (it+1 < 16) {
      nx0 = gld2(xp + (2*it+2)*BB); nh0 = gld2(hp + (2*it+2)*BB);
      nx1 = gld2(xp + (2*it+3)*BB); nh1 = gld2(hp + (2*it+3)*BB);
    }
    {
      f16v wi = wp[it*4+0], wh = wp[it*4+1];
      #pragma unroll
      for (int r = 0; r < 16; ++r) {
        acc[2*r]   += wi[r]*qx0.x + wh[r]*qh0.x;
        acc[2*r+1] += wi[r]*qx0.y + wh[r]*qh0.y;
      }
    }
    {
      f16v wi = wp[it*4+2], wh = wp[it*4+3];
      #pragma unroll
      for (int r = 0; r < 16; ++r) {
        acc[2*r]   += wi[r]*qx1.x + wh[r]*qh1.x;
        acc[2*r+1] += wi[r]*qx1.y + wh[r]*qh1.y;
      }
    }
    qx0 = nx0; qh0 = nh0; qx1 = nx1; qh1 = nh1;
  }
  #pragma unroll
  for (int r = 0; r < 16; ++r)
    *(float2*)(red + (size_t)(ks*16 + r)*128 + 2*lane) = make_float2(acc[2*r], acc[2*r+1]);
  __syncthreads();
  if (tid < 512) {
    const int lhu = tid >> 7, b = tid & 127;
    float g4[4];
    #pragma unroll
    for (int gg = 0; gg < 4; ++gg) {
      float s = bias[lhu*4+gg];
      #pragma unroll
      for (int q = 0; q < 16; ++q) s += red[(size_t)(q*16 + lhu*4+gg)*128 + b];
      g4[gg] = s;
    }
    float ig=sigm(g4[0]), fg=sigm(g4[1]), gv=tanhf(g4[2]), og=sigm(g4[3]);
    float cn = fg*creg + ig*gv;
    creg = cn;
    gst(hdst + (size_t)(i*4+lhu)*BB + j*128 + b, og*tanhf(cn));
  }
}

// fc2 phase: wave ks (16): 32-k slice, 4 rows, 128 b (2/lane).
__device__ __forceinline__ void fc2_phase(const float* __restrict__ h2src,
    const float* __restrict__ wsTf, float* __restrict__ yb,
    const float* lds_bc, const float* condY_l, float* __restrict__ red,
    int i, int j, int tid)
{
  const int lane = tid & 63, ks = tid >> 6;
  cf8v* wpf = (cf8v*)cptr(wsTf + (size_t)ks*128);   // [k][4], f8v = 2 k
  const int bo = j*128 + 2*lane;
  const float* hp = h2src + (size_t)(ks*32)*BB + bo;
  float acc[8];
  #pragma unroll
  for (int r = 0; r < 8; ++r) acc[r] = 0.f;
  float2 qh0, qh1, nh0, nh1;
  qh0 = gld2(hp); qh1 = gld2(hp + BB);
  #pragma unroll 1
  for (int it = 0; it < 16; ++it) {
    if (it+1 < 16) {
      nh0 = gld2(hp + (2*it+2)*BB);
      nh1 = gld2(hp + (2*it+3)*BB);
    }
    f8v w = wpf[it];
    #pragma unroll
    for (int r = 0; r < 4; ++r) {
      acc[2*r]   += w[r]*qh0.x + w[4+r]*qh1.x;
      acc[2*r+1] += w[r]*qh0.y + w[4+r]*qh1.y;
    }
    qh0 = nh0; qh1 = nh1;
  }
  #pragma unroll
  for (int r = 0; r < 4; ++r)
    *(float2*)(red + (size_t)(ks*4+r)*128 + 2*lane) = make_float2(acc[2*r], acc[2*r+1]);
  __syncthreads();
  if (tid < 512) {
    int r = tid >> 7, b = tid & 127;
    float s = lds_bc[r] + condY_l[r*128+b];
    #pragma unroll
    for (int q = 0; q < 16; ++q) s += red[(size_t)(q*4+r)*128 + b];
    gst(yb + (size_t)(i*4+r)*BB + j*128 + b, lrelu(s));
  }
}

extern "C" __global__ void __launch_bounds__(NTHR)
decoder_kernel(const float* __restrict__ h0, const float* __restrict__ c0,
               const float* __restrict__ conds, const float* __restrict__ emb,
               const float* __restrict__ wsTW, const float* __restrict__ bih,
               const float* __restrict__ bhh, const float* __restrict__ fcW,
               const float* __restrict__ fcb, const float* __restrict__ fc2W,
               const float* __restrict__ fc2b, const float* __restrict__ fc3W,
               const float* __restrict__ fc3b,
               float* __restrict__ out, unsigned* bar, float* wsf)
{
  const int w = blockIdx.x;
  const int i = w & 127, j = w >> 7;
  const int grp = w & 7;
  const int tid = threadIdx.x;

  float* xbuf  = wsf;
  float* h1a = wsf + 1*SZ;  float* h1b = wsf + 2*SZ;
  float* h2a = wsf + 3*SZ;  float* h2b = wsf + 4*SZ;
  float* yb  = wsf + 5*SZ;
  float* condb = wsf + 6*SZ;
  const float* wTi  = wsTW + (size_t)i*32768;
  const float* wsTf = wsTW + FC2OFF + (size_t)i*2048;

  __shared__ float red[32768];        // 128KB reduction scratch -> 1 WG/CU
  __shared__ float lds_y[HH];
  __shared__ float part[NOUT][17];
  __shared__ float condY_l[512];
  __shared__ float lds_b1[16], lds_b2[16], lds_bc[4];
  __shared__ int   lds_act;

  if (tid < 16) {
    int u2 = tid >> 2, g = tid & 3;
    int hu = i*4 + u2;
    lds_b1[tid] = bih[g*HH+hu] + bhh[g*HH+hu];
    lds_b2[tid] = bih[4*HH + g*HH+hu] + bhh[4*HH + g*HH+hu];
  }
  if (tid < 4) lds_bc[tid] = fc2b[i*4 + tid];

  // ---- init: exchanged state (normal stores; published by the fenced barrier) ----
  {
    int u = tid >> 8, b = tid & 255;
    int hug = i*4 + u;
    h1a[(size_t)hug*BB + b] = h0[(size_t)b*HH + hug];
    h2a[(size_t)hug*BB + b] = h0[(size_t)(BB+b)*HH + hug];
    xbuf[(size_t)hug*BB + b] = (hug < HH-1) ? emb[hug] : 0.0f;  // emb[SOS=0], dur=0
    const float* crow = conds + (size_t)b*CD;
    cfloat* fr = cptr(fcW + (size_t)hug*CD);
    float s = fcb[hug];
    #pragma unroll 4
    for (int q = 0; q < CD; q += 4)
      s += fr[q]*crow[q] + fr[q+1]*crow[q+1] + fr[q+2]*crow[q+2] + fr[q+3]*crow[q+3];
    condb[(size_t)hug*BB + b] = lrelu(s);
  }
  float c1 = 0.f, c2 = 0.f;
  if (tid < 512) {
    int lhu = tid >> 7, b = tid & 127;
    int hug = i*4 + lhu, bg = j*128 + b;
    c1 = c0[(size_t)bg*HH + hug];
    c2 = c0[(size_t)(BB+bg)*HH + hug];
  }
  unsigned ep = 0;
  gbar(bar, ep++, grp, true);

  // condY_l[r][b]: cond-branch through fc2 (step-invariant, WG-private in LDS)
  if (tid < 512) {
    int r = tid >> 7, b = tid & 127, bg = j*128 + b;
    cfloat* wr = cptr(fc2W + (size_t)(i*4+r)*HH);
    float s = 0.f;
    #pragma unroll 4
    for (int k = 0; k < HH; ++k) s += wr[k]*condb[(size_t)k*BB + bg];
    condY_l[r*128 + b] = s;
  }
  __syncthreads();

  for (int t = 0; t < TT; ++t) {
    float* h1r = (t&1) ? h1b : h1a;  float* h1w = (t&1) ? h1a : h1b;
    float* h2r = (t&1) ? h2b : h2a;  float* h2w = (t&1) ? h2a : h2b;

    lstm_phase(wTi,         lds_b1, red, xbuf, h1r, h1w, c1, i, j, tid);
    gbar(bar, ep++, grp, false);
    lstm_phase(wTi + 16384, lds_b2, red, h1w, h2r, h2w, c2, i, j, tid);
    gbar(bar, ep++, grp, false);
    fc2_phase(h2w, wsTf, yb, lds_bc, condY_l, red, i, j, tid);
    gbar(bar, ep++, grp, false);
    // ---- phase D: WG w owns batch row w: fc3, argmax, next x ----
    {
      if (tid < 512) lds_y[tid] = gld(yb + (size_t)tid*BB + w);
      __syncthreads();
      int o = 0, kc = 0;
      bool active = false;
      if (tid < 512)      { o = tid & 31; kc = tid >> 5; active = true; }
      else if (tid < 528) { o = 32;       kc = tid - 512; active = true; }
      if (active) {
        float p = 0.f;
        const float* fw = fc3W + (size_t)o*HH + kc*32;
        #pragma unroll
        for (int k2 = 0; k2 < 32; ++k2) p += fw[k2] * lds_y[kc*32 + k2];
        part[o][kc] = p;
      }
      __syncthreads();
      float predv = -1e30f;
      if (tid < NOUT) {
        float s = fc3b[tid];
        #pragma unroll
        for (int kc2 = 0; kc2 < 16; ++kc2) s += part[tid][kc2];
        predv = s;
        out[(size_t)(w*TT + t)*NOUT + tid] = s;
      }
      if (tid < 64) {
        float v  = (tid < 32) ? predv : -1e30f;
        int  idx = tid;
        #pragma unroll
        for (int off = 32; off > 0; off >>= 1) {
          float ov = __shfl_xor(v, off);
          int   oi = __shfl_xor(idx, off);
          if (ov > v || (ov == v && oi < idx)) { v = ov; idx = oi; }
        }
        if (tid == 0) lds_act = idx;
      }
      __syncthreads();
      const int act = lds_act;
      if (tid < 512)
        gst(xbuf + (size_t)tid*BB + w, (tid < HH-1) ? emb[(size_t)act*(HH-1) + tid] : 1.0f);
    }
    gbar(bar, ep++, grp, false);
  }

  // ---- postprocess row w ----
  if (tid < TT) {
    const int s = tid;
    float* po = out + (size_t)(w*TT + s)*NOUT;
    float v[NOUT];
    #pragma unroll
    for (int o = 0; o < NOUT; ++o) v[o] = po[o];
    float m = v[0];
    #pragma unroll
    for (int o = 1; o < 32; ++o) m = fmaxf(m, v[o]);
    float sum = 0.f;
    #pragma unroll
    for (int o = 0; o < 32; ++o) sum += expf(v[o] - m);
    float lse = m + logf(sum);
    #pragma unroll
    for (int o = 0; o < 32; ++o) po[o] = v[o] - lse;
    float d = v[32];
    float dm = d;
    #pragma unroll
    for (int off = 32; off > 0; off >>= 1) dm = fmaxf(dm, __shfl_xor(dm, off));
    float e = expf(d - dm);
    float es = e;
    #pragma unroll
    for (int off = 32; off > 0; off >>= 1) es += __shfl_xor(es, off);
    po[32] = e / es;
  }
}

extern "C" void kernel_launch(void* const* d_in, const int* in_sizes, int n_in,
                              void* d_out, int out_size, void* d_ws, size_t ws_size,
                              hipStream_t stream) {
  const float* h0   = (const float*)d_in[1];
  const float* c0   = (const float*)d_in[2];
  const float* cnd  = (const float*)d_in[3];
  const float* emb  = (const float*)d_in[4];
  const float* Wih  = (const float*)d_in[5];
  const float* Whh  = (const float*)d_in[6];
  const float* bih  = (const float*)d_in[7];
  const float* bhh  = (const float*)d_in[8];
  const float* fcW  = (const float*)d_in[9];
  const float* fcb  = (const float*)d_in[10];
  const float* fc2W = (const float*)d_in[11];
  const float* fc2b = (const float*)d_in[12];
  const float* fc3W = (const float*)d_in[13];
  const float* fc3b = (const float*)d_in[14];

  unsigned* bar = (unsigned*)d_ws;
  float* wsf = (float*)((char*)d_ws + 1024);
  float* wsT = wsf + 7*SZ;

  (void)hipMemsetAsync(d_ws, 0, 1024, stream);

  hipLaunchKernelGGL(transpose_weights, dim3(128), dim3(256), 0, stream,
                     Wih, Whh, fc2W, wsT);
  hipLaunchKernelGGL(decoder_kernel, dim3(NWG), dim3(NTHR), 0, stream,
                     h0, c0, cnd, emb, wsT, bih, bhh, fcW, fcb,
                     fc2W, fc2b, fc3W, fc3b, (float*)d_out, bar, wsf);
}